// Round 6
// baseline (7880.910 us; speedup 1.0000x reference)
//
#include <hip/hip_runtime.h>

// OptNet KKT layer: out = normalize(M^{-1} K^T), M = c1*Phi + c2*I (SPD, n=4096, 512 RHS).
// Blocked fp32 Cholesky with lookahead: potrf(k+1) = block 0 of the syrk(k) dispatch.
// This round: 512-thread fused kernel (2 waves/SIMD), LDS-broadcast corner factor
// (no shfl chains), rsqrt in the column chain.

#define N    4096
#define NRHS 512
#define NB   128
#define LSTR 132   // padded LDS row stride for 128-wide rows
#define TSTR 136   // padded LDS row stride for t-major staging
#define BSTR 68    // padded LDS row stride for 64-wide RHS tiles
#define ASTR 36    // Tl row stride

// ---------------- scalars ----------------
__global__ __launch_bounds__(256) void k_scalars(const float* __restrict__ imp,
                                                 const float* __restrict__ exc,
                                                 const float* __restrict__ gamma,
                                                 float* __restrict__ c) {
  __shared__ float red[256];
  int tid = threadIdx.x;
  float s = 0.0f;
  for (int i = tid; i < 1024; i += 256) { float x = imp[i], y = exc[i]; s += x * x + y * y; }
  red[tid] = s; __syncthreads();
  for (int w = 128; w > 0; w >>= 1) { if (tid < w) red[tid] += red[tid + w]; __syncthreads(); }
  if (tid == 0) { c[0] = red[0] / 512.0f; c[1] = gamma[0] / 512.0f; }
}

// ---------------- M = c1*Phi + c2*I ----------------
__global__ __launch_bounds__(256) void k_build_M(const float* __restrict__ Phi,
                                                 const float* __restrict__ c,
                                                 float* __restrict__ M) {
  int idx = blockIdx.x * 256 + threadIdx.x;
  int base = idx * 4;
  float4 p = *(const float4*)(Phi + base);
  float c1 = c[0], c2 = c[1];
  float4 m;
  m.x = c1 * p.x; m.y = c1 * p.y; m.z = c1 * p.z; m.w = c1 * p.w;
  int r = base >> 12, c0 = base & (N - 1);
  if (r == c0)     m.x += c2;
  if (r == c0 + 1) m.y += c2;
  if (r == c0 + 2) m.z += c2;
  if (r == c0 + 3) m.w += c2;
  *(float4*)(M + base) = m;
}

// ---------------- S[i][b] = K[b][i] ----------------
__global__ __launch_bounds__(256) void k_transpose(const float* __restrict__ K,
                                                   float* __restrict__ S) {
  __shared__ float t[32][33];
  int bi = blockIdx.x, bb = blockIdx.y;
  int tx = threadIdx.x & 31, ty = threadIdx.x >> 5;
  for (int r = 0; r < 4; ++r)
    t[ty + 8 * r][tx] = K[(size_t)(bb * 32 + ty + 8 * r) * N + bi * 32 + tx];
  __syncthreads();
  for (int r = 0; r < 4; ++r)
    S[(size_t)(bi * 32 + ty + 8 * r) * NRHS + bb * 32 + tx] = t[tx][ty + 8 * r];
}

struct SyrkSmem { float Pa[16][TSTR]; float Pb[16][TSTR]; };
struct AsmSmem  { float Tl[3][32][ASTR]; float dinv[NB]; float cb[32]; };
union USmem { SyrkSmem s; AsmSmem a; };

// ---------------- fused syrk(kdiag-panel k0) + lookahead potrf(kdiag) ----------------
// 512 threads. bid 0: potrf role; bid>=1: trailing syrk tile (lower-tri, excl (0,0)).
__global__ __launch_bounds__(512, 2) void k_syrk_potrf(float* __restrict__ M,
                                                       float* __restrict__ U,
                                                       float* __restrict__ UT,
                                                       int kdiag, int k0) {
  __shared__ float Lb[NB][LSTR];
  __shared__ float Us[NB][LSTR];
  __shared__ USmem un;
  int tid = threadIdx.x;
  int bid = blockIdx.x;
  int rr = (tid >> 4) * 4, cc = (tid & 15) * 8;

  if (bid > 0) {
    // ================= syrk role: C(br,bc) -= P_br P_bc^T =================
    int p = bid;
    int br = (int)((sqrtf(8.f * (float)p + 1.f) - 1.f) * 0.5f);
    while (((br + 1) * (br + 2)) / 2 <= p) ++br;
    while ((br * (br + 1)) / 2 > p) --br;
    int bc = p - (br * (br + 1)) / 2;
    int t0 = kdiag * NB;
    int r0 = t0 + br * NB, c0 = t0 + bc * NB;
    float acc[4][8] = {};
    for (int tch = 0; tch < NB; tch += 16) {
      for (int idx = tid; idx < 1024; idx += 512) {
        int sel = idx >> 9, id2 = idx & 511;
        int r = id2 >> 2, q = id2 & 3;
        const float4 v = *(const float4*)(M + (size_t)((sel ? c0 : r0) + r) * N + k0 + tch + 4 * q);
        float* dst = sel ? &un.s.Pb[0][0] : &un.s.Pa[0][0];
        dst[(4 * q + 0) * TSTR + r] = v.x;
        dst[(4 * q + 1) * TSTR + r] = v.y;
        dst[(4 * q + 2) * TSTR + r] = v.z;
        dst[(4 * q + 3) * TSTR + r] = v.w;
      }
      __syncthreads();
#pragma unroll 4
      for (int t = 0; t < 16; ++t) {
        float4 a0 = *(const float4*)&un.s.Pa[t][rr];
        float4 b0 = *(const float4*)&un.s.Pb[t][cc];
        float4 b1 = *(const float4*)&un.s.Pb[t][cc + 4];
        float av[4] = {a0.x, a0.y, a0.z, a0.w};
        float bv[8] = {b0.x, b0.y, b0.z, b0.w, b1.x, b1.y, b1.z, b1.w};
#pragma unroll
        for (int q = 0; q < 4; ++q)
#pragma unroll
          for (int w = 0; w < 8; ++w) acc[q][w] += av[q] * bv[w];
      }
      __syncthreads();
    }
    for (int q = 0; q < 4; ++q) {
      float* mp = M + (size_t)(r0 + rr + q) * N + c0 + cc;
      float4 x0 = *(float4*)mp, x1 = *((float4*)mp + 1);
      x0.x -= acc[q][0]; x0.y -= acc[q][1]; x0.z -= acc[q][2]; x0.w -= acc[q][3];
      x1.x -= acc[q][4]; x1.y -= acc[q][5]; x1.z -= acc[q][6]; x1.w -= acc[q][7];
      *(float4*)mp = x0; *((float4*)mp + 1) = x1;
    }
    return;
  }

  // ================= potrf role =================
  int kr = kdiag * NB;
  float accd[4][8] = {};
  if (k0 >= 0) {  // redundant diag update: D -= P P^T (P = M[kr.., k0..], symmetric operands)
    for (int tch = 0; tch < NB; tch += 16) {
      {
        int r = tid >> 2, q = tid & 3;
        const float4 v = *(const float4*)(M + (size_t)(kr + r) * N + k0 + tch + 4 * q);
        un.s.Pa[4 * q + 0][r] = v.x; un.s.Pa[4 * q + 1][r] = v.y;
        un.s.Pa[4 * q + 2][r] = v.z; un.s.Pa[4 * q + 3][r] = v.w;
      }
      __syncthreads();
#pragma unroll 4
      for (int t = 0; t < 16; ++t) {
        float4 a0 = *(const float4*)&un.s.Pa[t][rr];
        float4 b0 = *(const float4*)&un.s.Pa[t][cc];
        float4 b1 = *(const float4*)&un.s.Pa[t][cc + 4];
        float av[4] = {a0.x, a0.y, a0.z, a0.w};
        float bv[8] = {b0.x, b0.y, b0.z, b0.w, b1.x, b1.y, b1.z, b1.w};
#pragma unroll
        for (int q = 0; q < 4; ++q)
#pragma unroll
          for (int w = 0; w < 8; ++w) accd[q][w] += av[q] * bv[w];
      }
      __syncthreads();
    }
  }
  for (int idx = tid; idx < NB * 32; idx += 512) {
    int i = idx >> 5, f = idx & 31;
    *(float4*)&Lb[i][4 * f] = *(const float4*)(M + (size_t)(kr + i) * N + kr + 4 * f);
    *(float4*)&Us[i][4 * f] = make_float4(0.f, 0.f, 0.f, 0.f);
  }
  __syncthreads();
  if (k0 >= 0) {
    for (int q = 0; q < 4; ++q)
      for (int w = 0; w < 8; ++w)
        Lb[rr + q][cc + w] -= accd[q][w];
  }
  __syncthreads();

  int l = tid;
#pragma unroll 1
  for (int p = 0; p < 4; ++p) {
    int b0 = 32 * p;
    // ---- corner factor: register rows + LDS column broadcast, rsqrt chain ----
    if (tid < 32) {
      float r[32];
#pragma unroll
      for (int t = 0; t < 32; ++t) r[t] = Lb[b0 + l][b0 + t];
      volatile float* cb = un.a.cb;
#pragma unroll
      for (int j = 0; j < 32; ++j) {
        float d = __shfl(r[j], j);
        float invd = rsqrtf(d);
        if (l == j) { r[j] = d * invd; un.a.dinv[b0 + j] = invd; }
        else if (l > j) r[j] *= invd;
        cb[l] = r[j];
#pragma unroll
        for (int t = j + 1; t < 32; ++t) {
          float cjt = cb[t];              // uniform broadcast read, independent
          if (l >= t) r[t] -= r[j] * cjt;
        }
      }
#pragma unroll
      for (int t = 0; t < 32; ++t) if (t <= l) Lb[b0 + l][b0 + t] = r[t];
    }
    __syncthreads();
    // ---- corner inverse: lane l = column l of V, uniform LDS row reads ----
    if (tid < 32) {
      float x[32];
#pragma unroll
      for (int i = 0; i < 32; ++i) {
        float s = (l == i) ? 1.0f : 0.0f;
#pragma unroll
        for (int t = 0; t < i; ++t) s -= Lb[b0 + i][b0 + t] * x[t];
        x[i] = s * un.a.dinv[b0 + i];
      }
#pragma unroll
      for (int i = 0; i < 32; ++i) Us[b0 + i][b0 + l] = x[i];
    }
    __syncthreads();
    int base = b0 + 32;
    int nbl = NB - base;
    if (nbl > 0) {
      // ---- strip TRSM: rows below corner x V^T ----
      int cnt = nbl * 32;
      float pv[6];
#pragma unroll
      for (int e = 0; e < 6; ++e) {
        int idx = tid + e * 512;
        if (idx < cnt) {
          int r2 = idx >> 5, cc2 = idx & 31;
          float s = 0.0f;
#pragma unroll
          for (int t = 0; t < 32; ++t)
            s += Lb[base + r2][b0 + t] * Us[b0 + cc2][b0 + t];
          pv[e] = s;
        }
      }
      __syncthreads();
#pragma unroll
      for (int e = 0; e < 6; ++e) {
        int idx = tid + e * 512;
        if (idx < cnt) {
          int r2 = idx >> 5, cc2 = idx & 31;
          Lb[base + r2][b0 + cc2] = pv[e];
        }
      }
      __syncthreads();
      // ---- rank-32 trailing update (lower incl diag) ----
      int tot = nbl * nbl;
      for (int idx = tid; idx < tot; idx += 512) {
        int i = idx / nbl, j = idx - i * nbl;
        if (j <= i) {
          float4 a0 = *(const float4*)&Lb[base + i][b0];
          float4 a1 = *(const float4*)&Lb[base + i][b0 + 4];
          float4 a2 = *(const float4*)&Lb[base + i][b0 + 8];
          float4 a3 = *(const float4*)&Lb[base + i][b0 + 12];
          float4 a4 = *(const float4*)&Lb[base + i][b0 + 16];
          float4 a5 = *(const float4*)&Lb[base + i][b0 + 20];
          float4 a6 = *(const float4*)&Lb[base + i][b0 + 24];
          float4 a7 = *(const float4*)&Lb[base + i][b0 + 28];
          float4 b0v = *(const float4*)&Lb[base + j][b0];
          float4 b1v = *(const float4*)&Lb[base + j][b0 + 4];
          float4 b2v = *(const float4*)&Lb[base + j][b0 + 8];
          float4 b3v = *(const float4*)&Lb[base + j][b0 + 12];
          float4 b4v = *(const float4*)&Lb[base + j][b0 + 16];
          float4 b5v = *(const float4*)&Lb[base + j][b0 + 20];
          float4 b6v = *(const float4*)&Lb[base + j][b0 + 24];
          float4 b7v = *(const float4*)&Lb[base + j][b0 + 28];
          float s = a0.x*b0v.x + a0.y*b0v.y + a0.z*b0v.z + a0.w*b0v.w
                  + a1.x*b1v.x + a1.y*b1v.y + a1.z*b1v.z + a1.w*b1v.w
                  + a2.x*b2v.x + a2.y*b2v.y + a2.z*b2v.z + a2.w*b2v.w
                  + a3.x*b3v.x + a3.y*b3v.y + a3.z*b3v.z + a3.w*b3v.w
                  + a4.x*b4v.x + a4.y*b4v.y + a4.z*b4v.z + a4.w*b4v.w
                  + a5.x*b5v.x + a5.y*b5v.y + a5.z*b5v.z + a5.w*b5v.w
                  + a6.x*b6v.x + a6.y*b6v.y + a6.z*b6v.z + a6.w*b6v.w
                  + a7.x*b7v.x + a7.y*b7v.y + a7.z*b7v.z + a7.w*b7v.w;
          Lb[base + i][base + j] -= s;
        }
      }
      __syncthreads();
    }
  }
  // ---- assemble off-diag U blocks by diagonals: U_ij = -V_i (sum_t L_it U_tj) ----
  {
    int rr2 = tid >> 4, cc0 = (tid & 15) * 2;
#pragma unroll 1
    for (int d = 1; d <= 3; ++d) {
      int nb = 4 - d;
#pragma unroll 1
      for (int blk = 0; blk < nb; ++blk) {
        int bi = blk + d, bj = blk;
        float s0 = 0.f, s1 = 0.f;
        for (int t = 32 * bj; t < 32 * bi; ++t) {
          float a = Lb[32 * bi + rr2][t];
          s0 += a * Us[t][32 * bj + cc0];
          s1 += a * Us[t][32 * bj + cc0 + 1];
        }
        un.a.Tl[blk][rr2][cc0] = s0; un.a.Tl[blk][rr2][cc0 + 1] = s1;
      }
      __syncthreads();
#pragma unroll 1
      for (int blk = 0; blk < nb; ++blk) {
        int bi = blk + d, bj = blk;
        float s0 = 0.f, s1 = 0.f;
#pragma unroll
        for (int t = 0; t < 32; ++t) {
          float a = Us[32 * bi + rr2][32 * bi + t];
          s0 += a * un.a.Tl[blk][t][cc0];
          s1 += a * un.a.Tl[blk][t][cc0 + 1];
        }
        Us[32 * bi + rr2][32 * bj + cc0] = -s0;
        Us[32 * bi + rr2][32 * bj + cc0 + 1] = -s1;
      }
      __syncthreads();
    }
  }
  // ---- write L, U, UT ----
  for (int idx = tid; idx < NB * 32; idx += 512) {
    int i = idx >> 5, f = idx & 31;
    *(float4*)(M + (size_t)(kr + i) * N + kr + 4 * f) = *(const float4*)&Lb[i][4 * f];
    *(float4*)(U + (size_t)i * NB + 4 * f) = *(const float4*)&Us[i][4 * f];
    float4 v;
    v.x = Us[4 * f + 0][i]; v.y = Us[4 * f + 1][i];
    v.z = Us[4 * f + 2][i]; v.w = Us[4 * f + 3][i];
    *(float4*)(UT + (size_t)i * NB + 4 * f) = v;
  }
}

// ---------------- panel TRSM as GEMM: P := P_old * U^T (512 threads) ----------------
__global__ __launch_bounds__(512, 2) void k_trsm(float* __restrict__ M,
                                                 const float* __restrict__ UT, int k0) {
  __shared__ float Ut[NB][LSTR];
  __shared__ float At[16][TSTR];
  int tid = threadIdx.x;
  int r0 = k0 + NB + blockIdx.x * NB;
  for (int idx = tid; idx < NB * 32; idx += 512) {
    int t = idx >> 5, f = idx & 31;
    *(float4*)&Ut[t][4 * f] = *(const float4*)(UT + (size_t)t * NB + 4 * f);
  }
  int i0 = (tid >> 4) * 4, j0 = (tid & 15) * 8;
  float acc[4][8] = {};
  for (int tch = 0; tch < NB; tch += 16) {
    {
      int r = tid >> 2, q = tid & 3;
      const float4 v = *(const float4*)(M + (size_t)(r0 + r) * N + k0 + tch + 4 * q);
      At[4 * q + 0][r] = v.x; At[4 * q + 1][r] = v.y;
      At[4 * q + 2][r] = v.z; At[4 * q + 3][r] = v.w;
    }
    __syncthreads();
#pragma unroll 4
    for (int t = 0; t < 16; ++t) {
      float4 a0 = *(const float4*)&At[t][i0];
      float4 u0 = *(const float4*)&Ut[tch + t][j0];
      float4 u1 = *(const float4*)&Ut[tch + t][j0 + 4];
      float av[4] = {a0.x, a0.y, a0.z, a0.w};
      float uv[8] = {u0.x, u0.y, u0.z, u0.w, u1.x, u1.y, u1.z, u1.w};
#pragma unroll
      for (int q = 0; q < 4; ++q)
#pragma unroll
        for (int w = 0; w < 8; ++w) acc[q][w] += av[q] * uv[w];
    }
    __syncthreads();
  }
  for (int q = 0; q < 4; ++q) {
    float* mp = M + (size_t)(r0 + i0 + q) * N + k0 + j0;
    float4 x0 = {acc[q][0], acc[q][1], acc[q][2], acc[q][3]};
    float4 x1 = {acc[q][4], acc[q][5], acc[q][6], acc[q][7]};
    *(float4*)mp = x0; *((float4*)mp + 1) = x1;
  }
}

// ---------------- fused forward solve step k ----------------
__global__ __launch_bounds__(256) void k_fsolve(float* __restrict__ S,
                                                float* __restrict__ X,
                                                const float* __restrict__ M,
                                                const float* __restrict__ UTk,
                                                int k0) {
  __shared__ float Xl[NB][BSTR];
  __shared__ float Aa[16][TSTR];
  __shared__ float Bb[16][BSTR];
  int tid = threadIdx.x;
  int b0 = blockIdx.x * 64;
  int d = blockIdx.y;
  int i0g = k0 + d * NB;
  int ii = (tid >> 3) * 4, bl = (tid & 7) * 8;
  float acc[4][8] = {};
  for (int tch = 0; tch < NB; tch += 16) {
    for (int idx = tid; idx < 512; idx += 256) {
      int t = idx >> 5, f = idx & 31;
      *(float4*)&Aa[t][4 * f] = *(const float4*)(UTk + (size_t)(tch + t) * NB + 4 * f);
    }
    {
      int t = tid >> 4, f = tid & 15;
      *(float4*)&Bb[t][4 * f] = *(const float4*)(S + (size_t)(k0 + tch + t) * NRHS + b0 + 4 * f);
    }
    __syncthreads();
#pragma unroll 4
    for (int t = 0; t < 16; ++t) {
      float4 a0 = *(const float4*)&Aa[t][ii];
      float4 b0v = *(const float4*)&Bb[t][bl];
      float4 b1v = *(const float4*)&Bb[t][bl + 4];
      float av[4] = {a0.x, a0.y, a0.z, a0.w};
      float bv[8] = {b0v.x, b0v.y, b0v.z, b0v.w, b1v.x, b1v.y, b1v.z, b1v.w};
#pragma unroll
      for (int q = 0; q < 4; ++q)
#pragma unroll
        for (int w = 0; w < 8; ++w) acc[q][w] += av[q] * bv[w];
    }
    __syncthreads();
  }
  if (d == 0) {
    for (int q = 0; q < 4; ++q) {
      float* xp = X + (size_t)(k0 + ii + q) * NRHS + b0 + bl;
      float4 x0 = {acc[q][0], acc[q][1], acc[q][2], acc[q][3]};
      float4 x1 = {acc[q][4], acc[q][5], acc[q][6], acc[q][7]};
      *(float4*)xp = x0; *((float4*)xp + 1) = x1;
    }
    return;
  }
  for (int q = 0; q < 4; ++q) {
    float4 x0 = {acc[q][0], acc[q][1], acc[q][2], acc[q][3]};
    float4 x1 = {acc[q][4], acc[q][5], acc[q][6], acc[q][7]};
    *(float4*)&Xl[ii + q][bl] = x0; *(float4*)&Xl[ii + q][bl + 4] = x1;
  }
  __syncthreads();
  float acc2[4][8] = {};
  for (int tch = 0; tch < NB; tch += 16) {
    for (int idx = tid; idx < 512; idx += 256) {
      int r = idx >> 2, q = idx & 3;
      const float4 v = *(const float4*)(M + (size_t)(i0g + r) * N + k0 + tch + 4 * q);
      Aa[4 * q + 0][r] = v.x; Aa[4 * q + 1][r] = v.y;
      Aa[4 * q + 2][r] = v.z; Aa[4 * q + 3][r] = v.w;
    }
    __syncthreads();
#pragma unroll 4
    for (int t = 0; t < 16; ++t) {
      float4 a0 = *(const float4*)&Aa[t][ii];
      float4 b0v = *(const float4*)&Xl[tch + t][bl];
      float4 b1v = *(const float4*)&Xl[tch + t][bl + 4];
      float av[4] = {a0.x, a0.y, a0.z, a0.w};
      float bv[8] = {b0v.x, b0v.y, b0v.z, b0v.w, b1v.x, b1v.y, b1v.z, b1v.w};
#pragma unroll
      for (int q = 0; q < 4; ++q)
#pragma unroll
        for (int w = 0; w < 8; ++w) acc2[q][w] += av[q] * bv[w];
    }
    __syncthreads();
  }
  for (int q = 0; q < 4; ++q) {
    float* sp = S + (size_t)(i0g + ii + q) * NRHS + b0 + bl;
    float4 x0 = *(float4*)sp, x1 = *((float4*)sp + 1);
    x0.x -= acc2[q][0]; x0.y -= acc2[q][1]; x0.z -= acc2[q][2]; x0.w -= acc2[q][3];
    x1.x -= acc2[q][4]; x1.y -= acc2[q][5]; x1.z -= acc2[q][6]; x1.w -= acc2[q][7];
    *(float4*)sp = x0; *((float4*)sp + 1) = x1;
  }
}

// ---------------- fused backward solve step k (descending) ----------------
__global__ __launch_bounds__(256) void k_bsolve(float* __restrict__ X,
                                                float* __restrict__ S,
                                                const float* __restrict__ M,
                                                const float* __restrict__ Uk,
                                                int k0) {
  __shared__ float Xl[NB][BSTR];
  __shared__ float Aa[16][TSTR];
  __shared__ float Bb[16][BSTR];
  int tid = threadIdx.x;
  int b0 = blockIdx.x * 64;
  int d = blockIdx.y;
  int i0g = k0 - d * NB;
  int ii = (tid >> 3) * 4, bl = (tid & 7) * 8;
  float acc[4][8] = {};
  for (int tch = 0; tch < NB; tch += 16) {
    for (int idx = tid; idx < 512; idx += 256) {
      int t = idx >> 5, f = idx & 31;
      *(float4*)&Aa[t][4 * f] = *(const float4*)(Uk + (size_t)(tch + t) * NB + 4 * f);
    }
    {
      int t = tid >> 4, f = tid & 15;
      *(float4*)&Bb[t][4 * f] = *(const float4*)(X + (size_t)(k0 + tch + t) * NRHS + b0 + 4 * f);
    }
    __syncthreads();
#pragma unroll 4
    for (int t = 0; t < 16; ++t) {
      float4 a0 = *(const float4*)&Aa[t][ii];
      float4 b0v = *(const float4*)&Bb[t][bl];
      float4 b1v = *(const float4*)&Bb[t][bl + 4];
      float av[4] = {a0.x, a0.y, a0.z, a0.w};
      float bv[8] = {b0v.x, b0v.y, b0v.z, b0v.w, b1v.x, b1v.y, b1v.z, b1v.w};
#pragma unroll
      for (int q = 0; q < 4; ++q)
#pragma unroll
        for (int w = 0; w < 8; ++w) acc[q][w] += av[q] * bv[w];
    }
    __syncthreads();
  }
  if (d == 0) {
    for (int q = 0; q < 4; ++q) {
      float* sp = S + (size_t)(k0 + ii + q) * NRHS + b0 + bl;
      float4 x0 = {acc[q][0], acc[q][1], acc[q][2], acc[q][3]};
      float4 x1 = {acc[q][4], acc[q][5], acc[q][6], acc[q][7]};
      *(float4*)sp = x0; *((float4*)sp + 1) = x1;
    }
    return;
  }
  for (int q = 0; q < 4; ++q) {
    float4 x0 = {acc[q][0], acc[q][1], acc[q][2], acc[q][3]};
    float4 x1 = {acc[q][4], acc[q][5], acc[q][6], acc[q][7]};
    *(float4*)&Xl[ii + q][bl] = x0; *(float4*)&Xl[ii + q][bl + 4] = x1;
  }
  __syncthreads();
  float acc2[4][8] = {};
  for (int tch = 0; tch < NB; tch += 16) {
    for (int idx = tid; idx < 512; idx += 256) {
      int t = idx >> 5, f = idx & 31;
      *(float4*)&Aa[t][4 * f] = *(const float4*)(M + (size_t)(k0 + tch + t) * N + i0g + 4 * f);
    }
    __syncthreads();
#pragma unroll 4
    for (int t = 0; t < 16; ++t) {
      float4 a0 = *(const float4*)&Aa[t][ii];
      float4 b0v = *(const float4*)&Xl[tch + t][bl];
      float4 b1v = *(const float4*)&Xl[tch + t][bl + 4];
      float av[4] = {a0.x, a0.y, a0.z, a0.w};
      float bv[8] = {b0v.x, b0v.y, b0v.z, b0v.w, b1v.x, b1v.y, b1v.z, b1v.w};
#pragma unroll
      for (int q = 0; q < 4; ++q)
#pragma unroll
        for (int w = 0; w < 8; ++w) acc2[q][w] += av[q] * bv[w];
    }
    __syncthreads();
  }
  for (int q = 0; q < 4; ++q) {
    float* xp = X + (size_t)(i0g + ii + q) * NRHS + b0 + bl;
    float4 x0 = *(float4*)xp, x1 = *((float4*)xp + 1);
    x0.x -= acc2[q][0]; x0.y -= acc2[q][1]; x0.z -= acc2[q][2]; x0.w -= acc2[q][3];
    x1.x -= acc2[q][4]; x1.y -= acc2[q][5]; x1.z -= acc2[q][6]; x1.w -= acc2[q][7];
    *(float4*)xp = x0; *((float4*)xp + 1) = x1;
  }
}

// ---------------- denom + normalize + transpose to output ----------------
__global__ __launch_bounds__(256) void k_final(const float* __restrict__ S,
                                               const float* __restrict__ K,
                                               const float* __restrict__ a_ptr,
                                               float* __restrict__ out) {
  __shared__ float red[256];
  int b = blockIdx.x, tid = threadIdx.x;
  float s = 0.0f;
  for (int i = tid; i < N; i += 256) s += S[(size_t)i * NRHS + b] * K[(size_t)b * N + i];
  red[tid] = s; __syncthreads();
  for (int w = 128; w > 0; w >>= 1) { if (tid < w) red[tid] += red[tid + w]; __syncthreads(); }
  float inv = 1.0f / (a_ptr[0] * red[0]);
  for (int i = tid; i < N; i += 256) out[(size_t)b * N + i] = S[(size_t)i * NRHS + b] * inv;
}

extern "C" void kernel_launch(void* const* d_in, const int* in_sizes, int n_in,
                              void* d_out, int out_size, void* d_ws, size_t ws_size,
                              hipStream_t stream) {
  const float* Kb    = (const float*)d_in[0];
  const float* a     = (const float*)d_in[1];
  const float* exc   = (const float*)d_in[2];
  const float* imp   = (const float*)d_in[3];
  const float* Phi   = (const float*)d_in[4];
  const float* gamma = (const float*)d_in[5];
  float* out = (float*)d_out;

  float* M  = (float*)d_ws;                        // n*n            (64 MiB)
  float* S  = M + (size_t)N * N;                   // n*NRHS         (8 MiB)
  float* X  = S + (size_t)N * NRHS;                // n*NRHS         (8 MiB)
  float* U  = X + (size_t)N * NRHS;                // 32 * 128*128   (2 MiB)
  float* UT = U + (size_t)32 * NB * NB;            // 32 * 128*128   (2 MiB)
  float* c  = UT + (size_t)32 * NB * NB;           // scalars

  k_scalars<<<1, 256, 0, stream>>>(imp, exc, gamma, c);
  k_build_M<<<N * N / 1024, 256, 0, stream>>>(Phi, c, M);
  k_transpose<<<dim3(N / 32, NRHS / 32), 256, 0, stream>>>(Kb, S);

  // potrf(0) standalone (no panel update, no trailing tiles)
  k_syrk_potrf<<<1, 512, 0, stream>>>(M, U, UT, 0, -1);
  for (int k = 0; k <= 30; ++k) {
    int k0 = k * NB;
    k_trsm<<<31 - k, 512, 0, stream>>>(M, UT + (size_t)k * NB * NB, k0);
    int T = 31 - k;
    int pairs = (T * (T + 1)) / 2;   // block 0 = lookahead potrf(k+1), rest = tri syrk tiles
    k_syrk_potrf<<<pairs, 512, 0, stream>>>(M, U + (size_t)(k + 1) * NB * NB,
                                            UT + (size_t)(k + 1) * NB * NB, k + 1, k0);
  }
  for (int k = 0; k < 32; ++k)
    k_fsolve<<<dim3(NRHS / 64, 32 - k), 256, 0, stream>>>(S, X, M, UT + (size_t)k * NB * NB, k * NB);
  for (int k = 31; k >= 0; --k)
    k_bsolve<<<dim3(NRHS / 64, k + 1), 256, 0, stream>>>(X, S, M, U + (size_t)k * NB * NB, k * NB);
  k_final<<<NRHS, 256, 0, stream>>>(S, Kb, a, out);
}